// Round 1
// baseline (4073.790 us; speedup 1.0000x reference)
//
#include <hip/hip_runtime.h>
#include <hip/hip_bf16.h>
#include <stdint.h>

// Problem constants
#define B_    8
#define CIN   64
#define COUT  64
#define HW_   256
#define KS    31
#define PADDED 288   // padded spatial dim for P (pad offset 15, +2 slack)
#define CG    8      // channels per group
#define NG    8      // number of channel groups (CIN/CG)
#define TILE  16     // output spatial tile (both dims)
#define PATCH 48     // staged patch rows/cols (16+31-1=46 real, padded to 48)

typedef __attribute__((ext_vector_type(8))) short short8;
typedef __attribute__((ext_vector_type(4))) float f32x4;

__device__ __forceinline__ short f2bf(float f) {
    __hip_bfloat16 h = __float2bfloat16(f);
    return __builtin_bit_cast(short, h);
}

// P layout: [b][g][y'][x'][cc] bf16, y',x' in [0,288), value = signal[b][g*8+cc][y'-15][x'-15] or 0
__global__ void pad_input_kernel(const float* __restrict__ sig, short* __restrict__ P) {
    int idx = blockIdx.x * 256 + threadIdx.x;   // total 8*8*288*288 = 5,308,416
    int x = idx % PADDED;
    int t = idx / PADDED;
    int y = t % PADDED;
    t /= PADDED;
    int g = t % NG;
    int b = t / NG;
    int ys = y - 15, xs = x - 15;
    bool in = (ys >= 0 && ys < HW_ && xs >= 0 && xs < HW_);
    const float* sp = sig + (((size_t)(b*CIN + g*CG) * HW_ + ys) * HW_ + xs);
    short8 v;
#pragma unroll
    for (int cc = 0; cc < CG; ++cc) {
        float f = in ? sp[(size_t)cc * HW_ * HW_] : 0.0f;
        v[cc] = f2bf(f);
    }
    *reinterpret_cast<short8*>(P + (size_t)idx * CG) = v;
}

// Wp layout: [g][u][vq][o][k], k in [0,32): k = dv*8+cc, v = vq*4+dv (v==31 zero-padded)
__global__ void pack_weight_kernel(const float* __restrict__ w, short* __restrict__ Wp) {
    int idx = blockIdx.x * 256 + threadIdx.x;   // total 8*31*8*64*32 = 4,063,232
    int k = idx & 31;
    int t = idx >> 5;
    int o = t & 63;
    t >>= 6;
    int vq = t & 7;
    t >>= 3;
    int u = t % KS;
    int g = t / KS;
    int dv = k >> 3, cc = k & 7;
    int v = vq * 4 + dv;
    float f = (v < KS) ? w[(((size_t)o * CIN + g * CG + cc) * KS + u) * KS + v] : 0.0f;
    Wp[idx] = f2bf(f);
}

// Main conv: one block = 64 out-ch x 16x16 spatial tile for one batch image.
// 4 waves; wave w owns rows y_local = 4w..4w+3 (64 positions). 16 MFMA accs (4 m-tiles x 4 rows).
__global__ __launch_bounds__(256, 2)
void conv_mfma_kernel(const short* __restrict__ P, const short* __restrict__ Wp,
                      const float* __restrict__ bias, float* __restrict__ out) {
    __shared__ __align__(16) short patch[PATCH * PATCH * CG];  // 36,864 B

    int bid = blockIdx.x;             // [0,2048)
    int b  = bid >> 8;
    int ty = (bid >> 4) & 15;
    int tx = bid & 15;
    int y0 = ty * TILE, x0 = tx * TILE;

    int tid  = threadIdx.x;
    int w    = tid >> 6;
    int lane = tid & 63;
    int quad = lane >> 4;
    int l15  = lane & 15;

    f32x4 acc[4][4];
#pragma unroll
    for (int m = 0; m < 4; ++m)
#pragma unroll
        for (int t = 0; t < 4; ++t)
            acc[m][t] = (f32x4){0.f, 0.f, 0.f, 0.f};

    for (int g = 0; g < NG; ++g) {
        __syncthreads();   // protect previous iteration's reads
        // ---- stage 48x48x8 bf16 patch via async global->LDS (16B per lane) ----
        const short* Pbase = P + (size_t)(b * NG + g) * PADDED * PADDED * CG;
        {
#pragma unroll
            for (int it = 0; it < 9; ++it) {
                int t = it * 256 + tid;        // [0, 2304)
                int r  = t / PATCH;
                int cl = t - r * PATCH;
                const short* gsrc = Pbase + ((size_t)(y0 + r) * PADDED + (x0 + cl)) * CG;
                __builtin_amdgcn_global_load_lds(
                    (const __attribute__((address_space(1))) void*)gsrc,
                    (__attribute__((address_space(3))) void*)(patch + (size_t)t * CG),
                    16, 0, 0);
            }
        }
        __syncthreads();   // implies vmcnt(0) drain of global_load_lds

        // ---- K loop: 31 u-taps x 8 v-quads; K-step = 8 ch x 4 v ----
        for (int u = 0; u < KS; ++u) {
#pragma unroll
            for (int vq = 0; vq < 8; ++vq) {
                const short* Ablk = Wp + (size_t)((g * KS + u) * 8 + vq) * (64 * 32);
                short8 a[4];
#pragma unroll
                for (int m = 0; m < 4; ++m)
                    a[m] = *reinterpret_cast<const short8*>(Ablk + ((m * 16 + l15) * 32 + quad * 8));
                short8 bf[4];
#pragma unroll
                for (int t = 0; t < 4; ++t) {
                    int row = w * 4 + t + u;
                    int col = l15 + vq * 4 + quad;
                    bf[t] = *reinterpret_cast<const short8*>(patch + (row * PATCH + col) * CG);
                }
#pragma unroll
                for (int m = 0; m < 4; ++m)
#pragma unroll
                    for (int t = 0; t < 4; ++t)
                        acc[m][t] = __builtin_amdgcn_mfma_f32_16x16x32_bf16(
                            a[m], bf[t], acc[m][t], 0, 0, 0);
            }
        }
    }

    // ---- epilogue: bias + store. D layout: col=lane&15 (x), row=quad*4+reg (o within m-tile)
#pragma unroll
    for (int m = 0; m < 4; ++m) {
#pragma unroll
        for (int r = 0; r < 4; ++r) {
            int o = m * 16 + quad * 4 + r;
            float bv = bias[o];
#pragma unroll
            for (int t = 0; t < 4; ++t) {
                int y = y0 + w * 4 + t;
                int x = x0 + l15;
                out[(((size_t)b * COUT + o) * HW_ + y) * HW_ + x] = acc[m][t][r] + bv;
            }
        }
    }
}

extern "C" void kernel_launch(void* const* d_in, const int* in_sizes, int n_in,
                              void* d_out, int out_size, void* d_ws, size_t ws_size,
                              hipStream_t stream) {
    const float* sig  = (const float*)d_in[0];
    const float* wgt  = (const float*)d_in[1];
    const float* bias = (const float*)d_in[2];
    float* out = (float*)d_out;

    // ws layout: Wp (4,063,232 shorts = 8,126,464 B) then P (42,467,328 shorts = 84,934,656 B)
    short* Wp = (short*)d_ws;
    short* P  = (short*)d_ws + 4063232;

    pack_weight_kernel<<<15872, 256, 0, stream>>>(wgt, Wp);
    pad_input_kernel<<<20736, 256, 0, stream>>>(sig, P);
    conv_mfma_kernel<<<2048, 256, 0, stream>>>(P, Wp, bias, out);
}

// Round 2
// 3900.920 us; speedup vs baseline: 1.0443x; 1.0443x over previous
//
#include <hip/hip_runtime.h>
#include <hip/hip_bf16.h>
#include <stdint.h>

// Problem constants
#define B_    8
#define CIN   64
#define COUT  64
#define HW_   256
#define KS    31
#define PADDED 288   // padded spatial dim for P (pad offset 15, +2 slack)
#define CG    8      // channels per group
#define NG    8      // number of channel groups (CIN/CG)
#define TILE  16     // output spatial tile (both dims)
#define PATCH 48     // staged patch rows/cols (16+31-1=46 real, padded to 48)

typedef __attribute__((ext_vector_type(8))) short short8;
typedef __attribute__((ext_vector_type(4))) float f32x4;

__device__ __forceinline__ short f2bf(float f) {
    __hip_bfloat16 h = __float2bfloat16(f);
    return __builtin_bit_cast(short, h);
}

// P layout: [b][g][y'][x'][cc] bf16, y',x' in [0,288), value = signal[b][g*8+cc][y'-15][x'-15] or 0
__global__ void pad_input_kernel(const float* __restrict__ sig, short* __restrict__ P) {
    int idx = blockIdx.x * 256 + threadIdx.x;   // total 8*8*288*288 = 5,308,416
    int x = idx % PADDED;
    int t = idx / PADDED;
    int y = t % PADDED;
    t /= PADDED;
    int g = t % NG;
    int b = t / NG;
    int ys = y - 15, xs = x - 15;
    bool in = (ys >= 0 && ys < HW_ && xs >= 0 && xs < HW_);
    const float* sp = sig + (((size_t)(b*CIN + g*CG) * HW_ + ys) * HW_ + xs);
    short8 v;
#pragma unroll
    for (int cc = 0; cc < CG; ++cc) {
        float f = in ? sp[(size_t)cc * HW_ * HW_] : 0.0f;
        v[cc] = f2bf(f);
    }
    *reinterpret_cast<short8*>(P + (size_t)idx * CG) = v;
}

// Wp layout: [g][u][vq][o][k], k in [0,32): k = dv*8+cc, v = vq*4+dv (v==31 zero-padded)
__global__ void pack_weight_kernel(const float* __restrict__ w, short* __restrict__ Wp) {
    int idx = blockIdx.x * 256 + threadIdx.x;   // total 8*31*8*64*32 = 4,063,232
    int k = idx & 31;
    int t = idx >> 5;
    int o = t & 63;
    t >>= 6;
    int vq = t & 7;
    t >>= 3;
    int u = t % KS;
    int g = t / KS;
    int dv = k >> 3, cc = k & 7;
    int v = vq * 4 + dv;
    float f = (v < KS) ? w[(((size_t)o * CIN + g * CG + cc) * KS + u) * KS + v] : 0.0f;
    Wp[idx] = f2bf(f);
}

// Main conv: one block = 64 out-ch x 16x16 spatial tile for one batch image.
// 4 waves; wave w owns rows y_local = 4w..4w+3 (64 positions). 16 MFMA accs (4 m-tiles x 4 rows).
// R2: explicit register double-buffer (ping-pong) of A-frags (global) and B-frags (LDS)
// so each K-step's loads land during the previous K-step's 16 MFMAs.
__global__ __launch_bounds__(256, 2)
void conv_mfma_kernel(const short* __restrict__ P, const short* __restrict__ Wp,
                      const float* __restrict__ bias, float* __restrict__ out) {
    __shared__ __align__(16) short patch[PATCH * PATCH * CG];  // 36,864 B

    int bid = blockIdx.x;             // [0,2048)
    int b  = bid >> 8;
    int ty = (bid >> 4) & 15;
    int tx = bid & 15;
    int y0 = ty * TILE, x0 = tx * TILE;

    int tid  = threadIdx.x;
    int w    = tid >> 6;
    int lane = tid & 63;
    int quad = lane >> 4;
    int l15  = lane & 15;

    // Per-lane invariant offsets
    const int a_off = l15 * 32 + quad * 8;          // within a 64x32 A block (element units)
    // B-frag base: row (w*4+t), col (l15+quad); vary by u*PATCH + vq*4 columns
    const short* bf_base[4];
#pragma unroll
    for (int t = 0; t < 4; ++t)
        bf_base[t] = patch + (((w * 4 + t) * PATCH) + l15 + quad) * CG;

    f32x4 acc[4][4];
#pragma unroll
    for (int m = 0; m < 4; ++m)
#pragma unroll
        for (int t = 0; t < 4; ++t)
            acc[m][t] = (f32x4){0.f, 0.f, 0.f, 0.f};

    for (int g = 0; g < NG; ++g) {
        __syncthreads();   // protect previous iteration's LDS reads
        // ---- stage 48x48x8 bf16 patch via async global->LDS (16B per lane) ----
        const short* Pbase = P + (size_t)(b * NG + g) * PADDED * PADDED * CG;
#pragma unroll
        for (int it = 0; it < 9; ++it) {
            int t = it * 256 + tid;        // [0, 2304)
            int r  = t / PATCH;
            int cl = t - r * PATCH;
            const short* gsrc = Pbase + ((size_t)(y0 + r) * PADDED + (x0 + cl)) * CG;
            __builtin_amdgcn_global_load_lds(
                (const __attribute__((address_space(1))) void*)gsrc,
                (__attribute__((address_space(3))) void*)(patch + (size_t)t * CG),
                16, 0, 0);
        }
        __syncthreads();   // drains vmcnt(0): staging complete

        const short* Wg = Wp + (size_t)g * KS * 8 * (64 * 32);

        // ---- software-pipelined K loop: 31 u-taps x 8 v-quads ----
        short8 a[2][4], bf[2][4];
        // prologue: load (u=0, vq=0) into buffer 0
#pragma unroll
        for (int m = 0; m < 4; ++m)
            a[0][m] = *reinterpret_cast<const short8*>(Wg + m * 16 * 32 + a_off);
#pragma unroll
        for (int t = 0; t < 4; ++t)
            bf[0][t] = *reinterpret_cast<const short8*>(bf_base[t]);

        for (int u = 0; u < KS; ++u) {
#pragma unroll
            for (int vq = 0; vq < 8; ++vq) {
                int p = vq & 1;
                int nu  = (vq == 7) ? u + 1 : u;
                int nvq = (vq + 1) & 7;
                if (nu < KS) {
                    const short* Ablk = Wg + (size_t)(nu * 8 + nvq) * (64 * 32);
#pragma unroll
                    for (int m = 0; m < 4; ++m)
                        a[p ^ 1][m] = *reinterpret_cast<const short8*>(Ablk + m * 16 * 32 + a_off);
#pragma unroll
                    for (int t = 0; t < 4; ++t)
                        bf[p ^ 1][t] = *reinterpret_cast<const short8*>(
                            bf_base[t] + (nu * PATCH + nvq * 4) * CG);
                }
#pragma unroll
                for (int m = 0; m < 4; ++m)
#pragma unroll
                    for (int t = 0; t < 4; ++t)
                        acc[m][t] = __builtin_amdgcn_mfma_f32_16x16x32_bf16(
                            a[p][m], bf[p][t], acc[m][t], 0, 0, 0);
            }
        }
    }

    // ---- epilogue: bias + store. D layout: col=lane&15 (x), row=quad*4+reg (o within m-tile)
#pragma unroll
    for (int m = 0; m < 4; ++m) {
#pragma unroll
        for (int r = 0; r < 4; ++r) {
            int o = m * 16 + quad * 4 + r;
            float bv = bias[o];
#pragma unroll
            for (int t = 0; t < 4; ++t) {
                int y = y0 + w * 4 + t;
                int x = x0 + l15;
                out[(((size_t)b * COUT + o) * HW_ + y) * HW_ + x] = acc[m][t][r] + bv;
            }
        }
    }
}

extern "C" void kernel_launch(void* const* d_in, const int* in_sizes, int n_in,
                              void* d_out, int out_size, void* d_ws, size_t ws_size,
                              hipStream_t stream) {
    const float* sig  = (const float*)d_in[0];
    const float* wgt  = (const float*)d_in[1];
    const float* bias = (const float*)d_in[2];
    float* out = (float*)d_out;

    // ws layout: Wp (4,063,232 shorts = 8,126,464 B) then P (42,467,328 shorts = 84,934,656 B)
    short* Wp = (short*)d_ws;
    short* P  = (short*)d_ws + 4063232;

    pack_weight_kernel<<<15872, 256, 0, stream>>>(wgt, Wp);
    pad_input_kernel<<<20736, 256, 0, stream>>>(sig, P);
    conv_mfma_kernel<<<2048, 256, 0, stream>>>(P, Wp, bias, out);
}